// Round 6
// baseline (51.440 us; speedup 1.0000x reference)
//
#include <hip/hip_runtime.h>
#include <math.h>

#define NEG_SLOPE 0.2f
#define LOG2E 1.44269504088896f

typedef _Float16 f16x8 __attribute__((ext_vector_type(8)));
typedef float f32x4 __attribute__((ext_vector_type(4)));

union PK8 { uint4 u4; _Float16 h[8]; };
union PK4 { uint2 u2; _Float16 h[4]; };
union PK1 { unsigned short u; _Float16 h; };

// ---------------------------------------------------------------------------
// Fused GAT layer, occupancy-restructured.
// Grid 512 = (b, h, half-of-i). 512 threads = 8 waves per block.
// Phase 1: slice-GEMM WxT[d][j] = sum_k W[h*32+d][k]*x[b][j][k], f16 MFMA,
//          K chunked by 32 (Xs = 512x32 f16 = 32 KB). Both halves duplicate
//          this (cheap: MfmaUtil was 4.8%) to avoid cross-block traffic.
// Phase 2: scores from f32 accumulators in-register; WxT -> f16 LDS, where
//          wxt ALIASES Xs (dead after last chunk; barrier orders overlap).
// Phase 3: softmax + PV (f16 MFMA, in-register P) + ELU for THIS HALF's
//          256 i-rows only (wave = 32 rows = 2 groups of 16).
// LDS = 16K (Ws) + 36K (pool) ~= 52.3 KB -> 3 blocks/CU capacity; grid 512
// -> 2 resident blocks/CU = 4 waves/SIMD (was 2), phases interleave across
// blocks. XCD affinity: b = bid&31 => batch b's 16 blocks all on XCD b%8.
// ---------------------------------------------------------------------------
__global__ __launch_bounds__(512) void gat_fused(const float* __restrict__ x,
                                                 const float* __restrict__ W,
                                                 const float* __restrict__ attn,
                                                 float* __restrict__ out) {
    __shared__ __align__(16) unsigned short Ws[32 * 256];     // [d][k] f16, swz (d&7)<<4
    __shared__ __align__(16) unsigned char pool[36 * 1024];   // Xs (32K) / wxt+stf+ssrc (36K)
    __shared__ float red_s[8];

    unsigned short* Xs  = (unsigned short*)pool;              // [j][k32] f16, row 64B
    unsigned short* wxt = (unsigned short*)pool;              // [d][j] f16, row 1024B (aliases Xs)
    float* stf  = (float*)(pool + 32 * 1024);                 // [512] s_tgt * LOG2E
    float* ssrc = (float*)(pool + 34 * 1024);                 // [512] s_src * LOG2E

    const int bid = blockIdx.x;
    const int b = bid & 31, h = (bid >> 5) & 7, half = bid >> 8;
    const int tid = threadIdx.x;
    const int w = tid >> 6, l = tid & 63;
    const int q = l >> 4, ln = l & 15;

    // ---- per-lane attn vector slices ----
    float av_s[2][4], av_t[2][4];
    #pragma unroll
    for (int dt = 0; dt < 2; ++dt)
        #pragma unroll
        for (int r = 0; r < 4; ++r) {
            int d = dt * 16 + q * 4 + r;
            av_s[dt][r] = attn[h * 64 + d];
            av_t[dt][r] = attn[h * 64 + 32 + d];
        }

    // ---- stage W slice: 32 rows x 256 k, f32 -> f16 ----
    #pragma unroll
    for (int p = 0; p < 4; ++p) {
        int idx = p * 512 + tid;            // 2048 float4 slots
        int d = idx >> 6, kq = idx & 63;
        float4 v = *(const float4*)(W + (size_t)(h * 32 + d) * 256 + kq * 4);
        PK4 pk;
        pk.h[0] = (_Float16)v.x; pk.h[1] = (_Float16)v.y;
        pk.h[2] = (_Float16)v.z; pk.h[3] = (_Float16)v.w;
        *(uint2*)((char*)Ws + ((d * 512 + kq * 8) ^ ((d & 7) << 4))) = pk.u2;
    }

    // ---- Phase 1: slice GEMM, K chunked by 32 (8 chunks) ----
    f32x4 gacc[2][4];
    #pragma unroll
    for (int dt = 0; dt < 2; ++dt)
        #pragma unroll
        for (int jt = 0; jt < 4; ++jt) gacc[dt][jt] = (f32x4){0.f, 0.f, 0.f, 0.f};

    const float* xb = x + (size_t)b * 512 * 256;
    for (int c = 0; c < 8; ++c) {
        __syncthreads();   // Xs reusable (first iter: also orders Ws writes)
        // stage x chunk: 512 rows x 32 k, f32 -> f16. 2 passes, 2 thr/row.
        #pragma unroll
        for (int pass = 0; pass < 2; ++pass) {
            int j = pass * 256 + (tid >> 1);
            int kh = (tid & 1) * 16;
            const float* src = xb + (size_t)j * 256 + c * 32 + kh;
            float4 v0 = *(const float4*)(src + 0);
            float4 v1 = *(const float4*)(src + 4);
            float4 v2 = *(const float4*)(src + 8);
            float4 v3 = *(const float4*)(src + 12);
            PK8 p0, p1;
            p0.h[0] = (_Float16)v0.x; p0.h[1] = (_Float16)v0.y;
            p0.h[2] = (_Float16)v0.z; p0.h[3] = (_Float16)v0.w;
            p0.h[4] = (_Float16)v1.x; p0.h[5] = (_Float16)v1.y;
            p0.h[6] = (_Float16)v1.z; p0.h[7] = (_Float16)v1.w;
            p1.h[0] = (_Float16)v2.x; p1.h[1] = (_Float16)v2.y;
            p1.h[2] = (_Float16)v2.z; p1.h[3] = (_Float16)v2.w;
            p1.h[4] = (_Float16)v3.x; p1.h[5] = (_Float16)v3.y;
            p1.h[6] = (_Float16)v3.z; p1.h[7] = (_Float16)v3.w;
            int base = j * 64 + kh * 2;
            *(uint4*)((char*)Xs + ((base) ^ ((j & 7) << 4))) = p0.u4;
            *(uint4*)((char*)Xs + ((base + 16) ^ ((j & 7) << 4))) = p1.u4;
        }
        __syncthreads();
        // compute: one K-step of 32 per chunk
        f16x8 af[2];
        #pragma unroll
        for (int dt = 0; dt < 2; ++dt) {
            int d = dt * 16 + ln;
            int bb = d * 512 + c * 64 + q * 16;
            uint4 raw = *(const uint4*)((const char*)Ws + (bb ^ ((d & 7) << 4)));
            PK8 pk; pk.u4 = raw;
            af[dt] = *(f16x8*)&pk;
        }
        #pragma unroll
        for (int jt = 0; jt < 4; ++jt) {
            int j = w * 64 + jt * 16 + ln;
            int bb = j * 64 + q * 16;
            uint4 raw = *(const uint4*)((const char*)Xs + (bb ^ ((j & 7) << 4)));
            PK8 pk; pk.u4 = raw;
            f16x8 bf = *(f16x8*)&pk;
            gacc[0][jt] = __builtin_amdgcn_mfma_f32_16x16x32_f16(af[0], bf, gacc[0][jt], 0, 0, 0);
            gacc[1][jt] = __builtin_amdgcn_mfma_f32_16x16x32_f16(af[1], bf, gacc[1][jt], 0, 0, 0);
        }
    }

    __syncthreads();   // Xs dead -> wxt may overwrite it

    // ---- Phase 2: scores in-register + WxT -> LDS (aliased region) ----
    // C layout: row(=d within tile) = q*4+r, col(=j) = ln.
    #pragma unroll
    for (int jt = 0; jt < 4; ++jt) {
        float ps = 0.f, pt = 0.f;
        #pragma unroll
        for (int dt = 0; dt < 2; ++dt)
            #pragma unroll
            for (int r = 0; r < 4; ++r) {
                float v = gacc[dt][jt][r];
                ps += v * av_s[dt][r];
                pt += v * av_t[dt][r];
            }
        ps += __shfl_xor(ps, 16); ps += __shfl_xor(ps, 32);
        pt += __shfl_xor(pt, 16); pt += __shfl_xor(pt, 32);
        int j = w * 64 + jt * 16 + ln;
        if (q == 0) { ssrc[j] = ps * LOG2E; stf[j] = pt * LOG2E; }
        #pragma unroll
        for (int dt = 0; dt < 2; ++dt)
            #pragma unroll
            for (int r = 0; r < 4; ++r) {
                int d = dt * 16 + q * 4 + r;
                PK1 hv; hv.h = (_Float16)gacc[dt][jt][r];
                *(unsigned short*)((char*)wxt + (((d << 10) + j * 2) ^ ((d & 7) << 4))) = hv.u;
            }
    }
    __syncthreads();

    // ---- Phase 3: softmax + PV + ELU for this half's 256 rows ----
    {
        float m = stf[tid];
        #pragma unroll
        for (int off = 32; off > 0; off >>= 1)
            m = fmaxf(m, __shfl_xor(m, off));
        if (l == 0) red_s[w] = m;
    }
    __syncthreads();
    float maxtK = red_s[0];
    #pragma unroll
    for (int ww = 1; ww < 8; ++ww) maxtK = fmaxf(maxtK, red_s[ww]);

    // wave owns 32 rows: i = half*256 + w*32 + g*16 + ln, g in {0,1}
    float ciK[2], miK[2];
    #pragma unroll
    for (int g = 0; g < 2; ++g) {
        int i = half * 256 + w * 32 + g * 16 + ln;
        float cc = ssrc[i];
        float cm = cc + maxtK;
        miK[g] = fmaxf(cm, NEG_SLOPE * cm);
        ciK[g] = cc;
    }

    f32x4 acc[2][2];
    #pragma unroll
    for (int g = 0; g < 2; ++g) {
        acc[g][0] = (f32x4){0.f, 0.f, 0.f, 0.f};
        acc[g][1] = (f32x4){0.f, 0.f, 0.f, 0.f};
    }
    float pd[2] = {0.f, 0.f};

    for (int kk = 0; kk < 16; ++kk) {
        const int j0 = kk * 32 + q * 8;
        float4 s0 = *(const float4*)(stf + j0);
        float4 s1 = *(const float4*)(stf + j0 + 4);
        float st[8] = {s0.x, s0.y, s0.z, s0.w, s1.x, s1.y, s1.z, s1.w};

        f16x8 bf[2];
        #pragma unroll
        for (int dt = 0; dt < 2; ++dt) {
            int d = dt * 16 + ln;
            int bb = d * 1024 + kk * 64 + q * 16;
            uint4 raw = *(const uint4*)((const char*)wxt + (bb ^ ((d & 7) << 4)));
            PK8 pk; pk.u4 = raw;
            bf[dt] = *(f16x8*)&pk;
        }

        #pragma unroll
        for (int g = 0; g < 2; ++g) {
            f16x8 pa;
            float s = 0.f;
            #pragma unroll
            for (int e = 0; e < 8; ++e) {
                float eK = ciK[g] + st[e];
                float lr = fmaxf(eK, NEG_SLOPE * eK);
                float p = exp2f(lr - miK[g]);
                s += p;
                pa[e] = (_Float16)p;
            }
            pd[g] += s;
            acc[g][0] = __builtin_amdgcn_mfma_f32_16x16x32_f16(pa, bf[0], acc[g][0], 0, 0, 0);
            acc[g][1] = __builtin_amdgcn_mfma_f32_16x16x32_f16(pa, bf[1], acc[g][1], 0, 0, 0);
        }
    }

    float inv[2];
    #pragma unroll
    for (int g = 0; g < 2; ++g) {
        float s = pd[g];
        s += __shfl_xor(s, 16);
        s += __shfl_xor(s, 32);
        inv[g] = 1.f / s;
    }
    #pragma unroll
    for (int g = 0; g < 2; ++g)
        #pragma unroll
        for (int dt = 0; dt < 2; ++dt)
            #pragma unroll
            for (int r = 0; r < 4; ++r) {
                int row = q * 4 + r;
                float dn = __shfl(inv[g], row);    // lane 'row' holds that row's denom
                float o = acc[g][dt][r] * dn;
                o = o > 0.f ? o : (__expf(o) - 1.f);
                size_t i = (size_t)(b * 512 + half * 256 + w * 32 + g * 16 + row);
                out[i * 256 + h * 32 + dt * 16 + ln] = o;
            }
}

// ---------------------------------------------------------------------------
extern "C" void kernel_launch(void* const* d_in, const int* in_sizes, int n_in,
                              void* d_out, int out_size, void* d_ws, size_t ws_size,
                              hipStream_t stream) {
    const float* x    = (const float*)d_in[0];   // (32,512,256)
    const float* W    = (const float*)d_in[1];   // (256,256)
    const float* attn = (const float*)d_in[2];   // (1,8,64)
    float* out = (float*)d_out;                  // (32,512,256)

    gat_fused<<<512, 512, 0, stream>>>(x, W, attn, out);
}

// Round 7
// 44.520 us; speedup vs baseline: 1.1554x; 1.1554x over previous
//
#include <hip/hip_runtime.h>
#include <math.h>

#define NEG_SLOPE 0.2f
#define LOG2E 1.44269504088896f

typedef _Float16 f16x8 __attribute__((ext_vector_type(8)));
typedef float f32x4 __attribute__((ext_vector_type(4)));

union PK8 { uint4 u4; _Float16 h[8]; };
union PK4 { uint2 u2; _Float16 h[4]; };
union PK1 { unsigned short u; _Float16 h; };

// ---------------------------------------------------------------------------
// Kernel A: Wx = x @ W.T via f16 MFMA, output f16 in [b*256 + (h*32+d)][j]
// layout (i.e. [bh][d][j], j fastest, 512 j per (b,h) slice) -> d_ws.
// Grid 512: block = 64 m-rows x 128 n-cols. 256 thr = 4 waves.
// Epilogue: C frags -> LDS transpose buffer (f16, swizzled) -> coalesced
// 16B global stores. x is converted f32->f16 exactly once per element.
// ---------------------------------------------------------------------------
__global__ __launch_bounds__(256) void gemm_wxt(const float* __restrict__ x,
                                                const float* __restrict__ W,
                                                unsigned short* __restrict__ wxtg) {
    __shared__ __align__(16) unsigned short xs[64 * 64];    // [i][k] f16, row 128B
    __shared__ __align__(16) unsigned short pool[128 * 64]; // ws / tbuf alias, 16KB
    unsigned short* ws = pool;   // [n][k] f16, row 128B, swz (n&7)<<4
    unsigned short* tb = pool;   // [n][j] f16, row 128B, swz (n&7)<<4 (after GEMM)

    const int tid = threadIdx.x;
    const int bid = blockIdx.x;
    const int m0 = (bid >> 1) * 64;
    const int n0 = (bid & 1) * 128;
    const int w = tid >> 6, l = tid & 63;
    const int q = l >> 4, ln = l & 15;
    const int iw = (w & 1) * 32, nw = (w >> 1) * 64;

    f32x4 acc[2][4];
    #pragma unroll
    for (int g = 0; g < 2; ++g)
        #pragma unroll
        for (int t = 0; t < 4; ++t) acc[g][t] = (f32x4){0.f, 0.f, 0.f, 0.f};

    for (int kc = 0; kc < 256; kc += 64) {
        __syncthreads();
        // stage x tile 64x64 f32 -> f16
        {
            const int i = tid >> 2, kq = tid & 3;
            const float* src = x + (size_t)(m0 + i) * 256 + kc + kq * 16;
            float4 v0 = *(const float4*)(src + 0);
            float4 v1 = *(const float4*)(src + 4);
            float4 v2 = *(const float4*)(src + 8);
            float4 v3 = *(const float4*)(src + 12);
            PK8 p0, p1;
            p0.h[0] = (_Float16)v0.x; p0.h[1] = (_Float16)v0.y;
            p0.h[2] = (_Float16)v0.z; p0.h[3] = (_Float16)v0.w;
            p0.h[4] = (_Float16)v1.x; p0.h[5] = (_Float16)v1.y;
            p0.h[6] = (_Float16)v1.z; p0.h[7] = (_Float16)v1.w;
            p1.h[0] = (_Float16)v2.x; p1.h[1] = (_Float16)v2.y;
            p1.h[2] = (_Float16)v2.z; p1.h[3] = (_Float16)v2.w;
            p1.h[4] = (_Float16)v3.x; p1.h[5] = (_Float16)v3.y;
            p1.h[6] = (_Float16)v3.z; p1.h[7] = (_Float16)v3.w;
            int b0 = i * 128 + kq * 32;
            *(uint4*)((char*)xs + (b0 ^ ((i & 7) << 4))) = p0.u4;
            *(uint4*)((char*)xs + ((b0 + 16) ^ ((i & 7) << 4))) = p1.u4;
        }
        // stage W tile 128x64 f32 -> f16 (8 passes of 16 rows)
        {
            const int kq = tid & 15, nr = tid >> 4;
            #pragma unroll
            for (int p = 0; p < 8; ++p) {
                int n = p * 16 + nr;
                float4 v = *(const float4*)(W + (size_t)(n0 + n) * 256 + kc + kq * 4);
                PK4 pk;
                pk.h[0] = (_Float16)v.x; pk.h[1] = (_Float16)v.y;
                pk.h[2] = (_Float16)v.z; pk.h[3] = (_Float16)v.w;
                *(uint2*)((char*)ws + ((n * 128 + kq * 8) ^ ((n & 7) << 4))) = pk.u2;
            }
        }
        __syncthreads();

        #pragma unroll
        for (int ks = 0; ks < 2; ++ks) {
            const int kb = ks * 64 + q * 16;
            f16x8 af[2];
            #pragma unroll
            for (int g = 0; g < 2; ++g) {
                int row = iw + g * 16 + ln;
                uint4 raw = *(const uint4*)((const char*)xs +
                            ((row * 128 + kb) ^ ((row & 7) << 4)));
                PK8 pk; pk.u4 = raw;
                af[g] = *(f16x8*)&pk;
            }
            #pragma unroll
            for (int t = 0; t < 4; ++t) {
                int n = nw + t * 16 + ln;
                uint4 raw = *(const uint4*)((const char*)ws +
                            ((n * 128 + kb) ^ ((n & 7) << 4)));
                PK8 pk; pk.u4 = raw;
                f16x8 bf = *(f16x8*)&pk;
                acc[0][t] = __builtin_amdgcn_mfma_f32_16x16x32_f16(af[0], bf, acc[0][t], 0, 0, 0);
                acc[1][t] = __builtin_amdgcn_mfma_f32_16x16x32_f16(af[1], bf, acc[1][t], 0, 0, 0);
            }
        }
    }

    __syncthreads();   // all waves done reading ws -> tb may overwrite
    // C frags -> transpose buffer: tb[n][j_local] f16
    #pragma unroll
    for (int g = 0; g < 2; ++g)
        #pragma unroll
        for (int t = 0; t < 4; ++t)
            #pragma unroll
            for (int r = 0; r < 4; ++r) {
                int n  = nw + t * 16 + ln;            // C col
                int jl = iw + g * 16 + q * 4 + r;     // C row
                PK1 hv; hv.h = (_Float16)acc[g][t][r];
                *(unsigned short*)((char*)tb + ((n * 128 + jl * 2) ^ ((n & 7) << 4))) = hv.u;
            }
    __syncthreads();
    // coalesced readout: 1024 16B-chunks, 4 per thread
    {
        const int b = m0 >> 9, j0 = m0 & 511;
        #pragma unroll
        for (int p = 0; p < 4; ++p) {
            int idx = p * 256 + tid;
            int n = idx >> 3, c = idx & 7;
            uint4 v = *(const uint4*)((const char*)tb + ((n * 128 + c * 16) ^ ((n & 7) << 4)));
            int nn = n0 + n;                          // = h*32 + d
            *(uint4*)(wxtg + ((size_t)(b * 256 + nn) * 512 + j0 + c * 8)) = v;
        }
    }
}

// ---------------------------------------------------------------------------
// Kernel B: scores + softmax + PV + ELU. Grid 1024 = (quarter, b, h).
// 512 thr = 8 waves; wave owns 16 i-rows. LDS ~36KB -> 4 blocks/CU.
// Stage WxT[32][512] f16 (straight copy, swizzled), scores from LDS tile,
// block max, then in-register P gen + f16 MFMA PV, ELU epilogue.
// ---------------------------------------------------------------------------
__global__ __launch_bounds__(512) void gat_attn(const unsigned short* __restrict__ wxtg,
                                                const float* __restrict__ attn,
                                                float* __restrict__ out) {
    __shared__ __align__(16) unsigned short wxt[32 * 512];  // [d][j] f16, row 1KB, swz (d&7)<<4
    __shared__ float stf[512];    // s_tgt * LOG2E
    __shared__ float ssrc[512];   // s_src * LOG2E
    __shared__ float red_s[8];

    const int bid = blockIdx.x;
    const int bh = bid & 255, q4 = bid >> 8;   // quarters of same bh share XCD (bh&7)
    const int b = bh >> 3, h = bh & 7;
    const int tid = threadIdx.x;
    const int w = tid >> 6, l = tid & 63;
    const int q = l >> 4, ln = l & 15;

    // ---- stage WxT slice: 32KB straight f16 copy ----
    {
        const unsigned short* src = wxtg + (size_t)bh * 32 * 512;
        const int d = tid >> 4, cs = tid & 15;
        #pragma unroll
        for (int p = 0; p < 4; ++p) {
            int c = p * 16 + cs;                       // 64 chunks per row
            uint4 v = *(const uint4*)(src + d * 512 + c * 8);
            *(uint4*)((char*)wxt + ((d * 1024 + c * 16) ^ ((d & 7) << 4))) = v;
        }
    }
    __syncthreads();

    // ---- scores from LDS tile: thread j = tid ----
    {
        const int j = tid;
        float ss = 0.f, st = 0.f;
        #pragma unroll
        for (int d = 0; d < 32; ++d) {
            PK1 hv;
            hv.u = *(const unsigned short*)((const char*)wxt +
                    ((d * 1024 + j * 2) ^ ((d & 7) << 4)));
            float v = (float)hv.h;
            ss += v * attn[h * 64 + d];
            st += v * attn[h * 64 + 32 + d];
        }
        ssrc[j] = ss * LOG2E;
        float stv = st * LOG2E;
        stf[j] = stv;
        // block max of stf (scaled; scale>0 so max commutes)
        float m = stv;
        #pragma unroll
        for (int off = 32; off > 0; off >>= 1)
            m = fmaxf(m, __shfl_xor(m, off));
        if (l == 0) red_s[w] = m;
    }
    __syncthreads();
    float maxtK = red_s[0];
    #pragma unroll
    for (int ww = 1; ww < 8; ++ww) maxtK = fmaxf(maxtK, red_s[ww]);

    // ---- per-lane row constants: wave owns rows i = q4*128 + w*16 + ln ----
    const int ibase = q4 * 128 + w * 16;
    float ciK, miK;
    {
        float cc = ssrc[ibase + ln];
        float cm = cc + maxtK;
        miK = fmaxf(cm, NEG_SLOPE * cm);
        ciK = cc;
    }

    f32x4 acc0 = (f32x4){0.f, 0.f, 0.f, 0.f};
    f32x4 acc1 = (f32x4){0.f, 0.f, 0.f, 0.f};
    float pd = 0.f;

    for (int kk = 0; kk < 16; ++kk) {
        const int j0 = kk * 32 + q * 8;
        float4 s0 = *(const float4*)(stf + j0);
        float4 s1 = *(const float4*)(stf + j0 + 4);
        float st[8] = {s0.x, s0.y, s0.z, s0.w, s1.x, s1.y, s1.z, s1.w};

        f16x8 bf[2];
        #pragma unroll
        for (int dt = 0; dt < 2; ++dt) {
            int d = dt * 16 + ln;
            int bb = d * 1024 + kk * 64 + q * 16;
            uint4 raw = *(const uint4*)((const char*)wxt + (bb ^ ((d & 7) << 4)));
            PK8 pk; pk.u4 = raw;
            bf[dt] = *(f16x8*)&pk;
        }

        f16x8 pa;
        float s = 0.f;
        #pragma unroll
        for (int e = 0; e < 8; ++e) {
            float eK = ciK + st[e];
            float lr = fmaxf(eK, NEG_SLOPE * eK);
            float p = exp2f(lr - miK);
            s += p;
            pa[e] = (_Float16)p;
        }
        pd += s;
        acc0 = __builtin_amdgcn_mfma_f32_16x16x32_f16(pa, bf[0], acc0, 0, 0, 0);
        acc1 = __builtin_amdgcn_mfma_f32_16x16x32_f16(pa, bf[1], acc1, 0, 0, 0);
    }

    // denom: sum over q groups -> every lane holds denom for row ln
    pd += __shfl_xor(pd, 16);
    pd += __shfl_xor(pd, 32);
    float inv = 1.f / pd;

    #pragma unroll
    for (int dt = 0; dt < 2; ++dt) {
        f32x4 a = dt ? acc1 : acc0;
        #pragma unroll
        for (int r = 0; r < 4; ++r) {
            int row = q * 4 + r;
            float dn = __shfl(inv, row);    // lane 'row' holds denom for i-local=row
            float o = a[r] * dn;
            o = o > 0.f ? o : (__expf(o) - 1.f);
            size_t i = (size_t)(b * 512 + ibase + row);
            out[i * 256 + h * 32 + dt * 16 + ln] = o;
        }
    }
}

// ---------------------------------------------------------------------------
extern "C" void kernel_launch(void* const* d_in, const int* in_sizes, int n_in,
                              void* d_out, int out_size, void* d_ws, size_t ws_size,
                              hipStream_t stream) {
    const float* x    = (const float*)d_in[0];   // (32,512,256)
    const float* W    = (const float*)d_in[1];   // (256,256)
    const float* attn = (const float*)d_in[2];   // (1,8,64)
    float* out = (float*)d_out;                  // (32,512,256)

    unsigned short* wxtg = (unsigned short*)d_ws;   // f16 [bh][d][j], 8.4 MB

    gemm_wxt<<<512, 256, 0, stream>>>(x, W, wxtg);
    gat_attn<<<1024, 512, 0, stream>>>(wxtg, attn, out);
}

// Round 8
// 39.241 us; speedup vs baseline: 1.3109x; 1.1346x over previous
//
#include <hip/hip_runtime.h>
#include <math.h>

#define NEG_SLOPE 0.2f
#define LOG2E 1.44269504088896f

#if __has_builtin(__builtin_amdgcn_exp2f)
#define EXP2F __builtin_amdgcn_exp2f
#else
#define EXP2F exp2f
#endif

typedef _Float16 f16x8 __attribute__((ext_vector_type(8)));
typedef float f32x4 __attribute__((ext_vector_type(4)));

union PK8 { uint4 u4; _Float16 h[8]; };
union PK1 { unsigned short u; _Float16 h; };

#define XN_CHUNKS (32 * 512 * 256 / 8)   // 524288 x-chunks of 8
#define WN_CHUNKS (256 * 256 / 8)        // 8192 W-chunks of 8

// ---------------------------------------------------------------------------
// Kernel 0: one-shot f32 -> f16 convert of x and W (each element exactly once).
// HBM-bound: 16.9 MB read + 8.5 MB write.
// ---------------------------------------------------------------------------
__global__ __launch_bounds__(256) void cvt_f16(const float* __restrict__ x,
                                               const float* __restrict__ W,
                                               unsigned short* __restrict__ xf,
                                               unsigned short* __restrict__ wf) {
    int idx = blockIdx.x * 256 + threadIdx.x;
    const float* src;
    unsigned short* dst;
    if (idx < XN_CHUNKS) {
        src = x + (size_t)idx * 8;
        dst = xf + (size_t)idx * 8;
    } else {
        int j = idx - XN_CHUNKS;
        if (j >= WN_CHUNKS) return;
        src = W + (size_t)j * 8;
        dst = wf + (size_t)j * 8;
    }
    float4 v0 = *(const float4*)(src);
    float4 v1 = *(const float4*)(src + 4);
    PK8 p;
    p.h[0] = (_Float16)v0.x; p.h[1] = (_Float16)v0.y;
    p.h[2] = (_Float16)v0.z; p.h[3] = (_Float16)v0.w;
    p.h[4] = (_Float16)v1.x; p.h[5] = (_Float16)v1.y;
    p.h[6] = (_Float16)v1.z; p.h[7] = (_Float16)v1.w;
    *(uint4*)dst = p.u4;
}

// ---------------------------------------------------------------------------
// Kernel A: Wx = x @ W.T via f16 MFMA (f16 inputs, zero converts).
// Output f16 [bh][d][j] (j fastest, 512 per slice) -> wxtg.
// Grid 512: block = 64 m x 128 n, 256 thr = 4 waves, K chunked by 64.
// Epilogue transposes C via LDS (aliases W-tile buffer) -> coalesced stores.
// ---------------------------------------------------------------------------
__global__ __launch_bounds__(256) void gemm_wxt(const unsigned short* __restrict__ xf,
                                                const unsigned short* __restrict__ wf,
                                                unsigned short* __restrict__ wxtg) {
    __shared__ __align__(16) unsigned short xs[64 * 64];    // [i][k] f16, row 128B
    __shared__ __align__(16) unsigned short pool[128 * 64]; // ws / tb alias, 16KB
    unsigned short* ws = pool;   // [n][k] f16, row 128B, swz (n&7)<<4
    unsigned short* tb = pool;   // [n][j] f16, row 128B, swz (n&7)<<4 (after GEMM)

    const int tid = threadIdx.x;
    const int bid = blockIdx.x;
    const int m0 = (bid >> 1) * 64;
    const int n0 = (bid & 1) * 128;
    const int w = tid >> 6, l = tid & 63;
    const int q = l >> 4, ln = l & 15;
    const int iw = (w & 1) * 32, nw = (w >> 1) * 64;

    f32x4 acc[2][4];
    #pragma unroll
    for (int g = 0; g < 2; ++g)
        #pragma unroll
        for (int t = 0; t < 4; ++t) acc[g][t] = (f32x4){0.f, 0.f, 0.f, 0.f};

    for (int kc = 0; kc < 256; kc += 64) {
        __syncthreads();
        // stage x tile 64x64 u16: 512 uint4, 2/thread
        #pragma unroll
        for (int p = 0; p < 2; ++p) {
            int idx = p * 256 + tid;
            int row = idx >> 3, c = idx & 7;
            uint4 v = *(const uint4*)(xf + (size_t)(m0 + row) * 256 + kc + c * 8);
            *(uint4*)((char*)xs + ((row * 128 + c * 16) ^ ((row & 7) << 4))) = v;
        }
        // stage W tile 128x64 u16: 1024 uint4, 4/thread
        #pragma unroll
        for (int p = 0; p < 4; ++p) {
            int idx = p * 256 + tid;
            int n = idx >> 3, c = idx & 7;
            uint4 v = *(const uint4*)(wf + (size_t)(n0 + n) * 256 + kc + c * 8);
            *(uint4*)((char*)ws + ((n * 128 + c * 16) ^ ((n & 7) << 4))) = v;
        }
        __syncthreads();

        #pragma unroll
        for (int ks = 0; ks < 2; ++ks) {
            const int kb = ks * 64 + q * 16;
            f16x8 af[2];
            #pragma unroll
            for (int g = 0; g < 2; ++g) {
                int row = iw + g * 16 + ln;
                uint4 raw = *(const uint4*)((const char*)xs +
                            ((row * 128 + kb) ^ ((row & 7) << 4)));
                PK8 pk; pk.u4 = raw;
                af[g] = *(f16x8*)&pk;
            }
            #pragma unroll
            for (int t = 0; t < 4; ++t) {
                int n = nw + t * 16 + ln;
                uint4 raw = *(const uint4*)((const char*)ws +
                            ((n * 128 + kb) ^ ((n & 7) << 4)));
                PK8 pk; pk.u4 = raw;
                f16x8 bf = *(f16x8*)&pk;
                acc[0][t] = __builtin_amdgcn_mfma_f32_16x16x32_f16(af[0], bf, acc[0][t], 0, 0, 0);
                acc[1][t] = __builtin_amdgcn_mfma_f32_16x16x32_f16(af[1], bf, acc[1][t], 0, 0, 0);
            }
        }
    }

    __syncthreads();   // done reading ws -> tb may overwrite
    // C frags -> transpose buffer tb[n][j_local] f16
    #pragma unroll
    for (int g = 0; g < 2; ++g)
        #pragma unroll
        for (int t = 0; t < 4; ++t)
            #pragma unroll
            for (int r = 0; r < 4; ++r) {
                int n  = nw + t * 16 + ln;            // C col
                int jl = iw + g * 16 + q * 4 + r;     // C row
                PK1 hv; hv.h = (_Float16)acc[g][t][r];
                *(unsigned short*)((char*)tb + ((n * 128 + jl * 2) ^ ((n & 7) << 4))) = hv.u;
            }
    __syncthreads();
    // coalesced readout: 1024 16B chunks, 4/thread
    {
        const int b = m0 >> 9, j0 = m0 & 511;
        #pragma unroll
        for (int p = 0; p < 4; ++p) {
            int idx = p * 256 + tid;
            int n = idx >> 3, c = idx & 7;
            uint4 v = *(const uint4*)((const char*)tb + ((n * 128 + c * 16) ^ ((n & 7) << 4)));
            int nn = n0 + n;                          // = h*32 + d
            *(uint4*)(wxtg + ((size_t)(b * 256 + nn) * 512 + j0 + c * 8)) = v;
        }
    }
}

// ---------------------------------------------------------------------------
// Kernel B: scores + softmax + PV + ELU. Grid 512 = (half, b, h).
// 512 thr = 8 waves; wave owns 32 i-rows (g=2) -> V-LDS traffic halved vs
// 16-rows/wave. LDS ~36KB + launch_bounds(512,4) -> 2 blocks/CU, 16 waves.
// Both halves of a bh land on the same XCD (bid%8 == (bid+256)%8).
// ---------------------------------------------------------------------------
__global__ __launch_bounds__(512, 4) void gat_attn(const unsigned short* __restrict__ wxtg,
                                                   const float* __restrict__ attn,
                                                   float* __restrict__ out) {
    __shared__ __align__(16) unsigned short wxt[32 * 512];  // [d][j] f16, row 1KB, swz (d&7)<<4
    __shared__ float stf[512];    // s_tgt * LOG2E
    __shared__ float ssrc[512];   // s_src * LOG2E
    __shared__ float red_s[8];

    const int bid = blockIdx.x;
    const int bh = bid & 255, half = bid >> 8;
    const int b = bh >> 3, h = bh & 7;
    const int tid = threadIdx.x;
    const int w = tid >> 6, l = tid & 63;
    const int q = l >> 4, ln = l & 15;

    // ---- stage WxT slice: 32KB straight f16 copy ----
    {
        const unsigned short* src = wxtg + (size_t)bh * 32 * 512;
        const int d = tid >> 4, cs = tid & 15;
        #pragma unroll
        for (int p = 0; p < 4; ++p) {
            int c = p * 16 + cs;
            uint4 v = *(const uint4*)(src + d * 512 + c * 8);
            *(uint4*)((char*)wxt + ((d * 1024 + c * 16) ^ ((d & 7) << 4))) = v;
        }
    }
    __syncthreads();

    // ---- scores from LDS tile: thread j = tid ----
    {
        const int j = tid;
        float ss = 0.f, st = 0.f;
        #pragma unroll
        for (int d = 0; d < 32; ++d) {
            PK1 hv;
            hv.u = *(const unsigned short*)((const char*)wxt +
                    ((d * 1024 + j * 2) ^ ((d & 7) << 4)));
            float v = (float)hv.h;
            ss += v * attn[h * 64 + d];
            st += v * attn[h * 64 + 32 + d];
        }
        ssrc[j] = ss * LOG2E;
        float stv = st * LOG2E;
        stf[j] = stv;
        float m = stv;
        #pragma unroll
        for (int off = 32; off > 0; off >>= 1)
            m = fmaxf(m, __shfl_xor(m, off));
        if (l == 0) red_s[w] = m;
    }
    __syncthreads();
    float maxtK = red_s[0];
    #pragma unroll
    for (int ww = 1; ww < 8; ++ww) maxtK = fmaxf(maxtK, red_s[ww]);

    // ---- wave owns rows i = half*256 + w*32 + g*16 + ln ----
    const int ibase = half * 256 + w * 32;
    float ciK[2], miK[2];
    #pragma unroll
    for (int g = 0; g < 2; ++g) {
        float cc = ssrc[ibase + g * 16 + ln];
        float cm = cc + maxtK;
        miK[g] = fmaxf(cm, NEG_SLOPE * cm);
        ciK[g] = cc;
    }

    f32x4 acc[2][2];
    #pragma unroll
    for (int g = 0; g < 2; ++g) {
        acc[g][0] = (f32x4){0.f, 0.f, 0.f, 0.f};
        acc[g][1] = (f32x4){0.f, 0.f, 0.f, 0.f};
    }
    float pd[2] = {0.f, 0.f};

    for (int kk = 0; kk < 16; ++kk) {
        const int j0 = kk * 32 + q * 8;
        float4 s0 = *(const float4*)(stf + j0);
        float4 s1 = *(const float4*)(stf + j0 + 4);
        float st[8] = {s0.x, s0.y, s0.z, s0.w, s1.x, s1.y, s1.z, s1.w};

        f16x8 bf[2];
        #pragma unroll
        for (int dt = 0; dt < 2; ++dt) {
            int d = dt * 16 + ln;
            int bb = d * 1024 + kk * 64 + q * 16;
            uint4 raw = *(const uint4*)((const char*)wxt + (bb ^ ((d & 7) << 4)));
            PK8 pk; pk.u4 = raw;
            bf[dt] = *(f16x8*)&pk;
        }

        #pragma unroll
        for (int g = 0; g < 2; ++g) {
            f16x8 pa;
            float s = 0.f;
            #pragma unroll
            for (int e = 0; e < 8; ++e) {
                float eK = ciK[g] + st[e];
                float lr = fmaxf(eK, NEG_SLOPE * eK);
                float p = EXP2F(lr - miK[g]);
                s += p;
                pa[e] = (_Float16)p;
            }
            pd[g] += s;
            acc[g][0] = __builtin_amdgcn_mfma_f32_16x16x32_f16(pa, bf[0], acc[g][0], 0, 0, 0);
            acc[g][1] = __builtin_amdgcn_mfma_f32_16x16x32_f16(pa, bf[1], acc[g][1], 0, 0, 0);
        }
    }

    float inv[2];
    #pragma unroll
    for (int g = 0; g < 2; ++g) {
        float s = pd[g];
        s += __shfl_xor(s, 16);
        s += __shfl_xor(s, 32);
        inv[g] = 1.f / s;
    }
    #pragma unroll
    for (int g = 0; g < 2; ++g)
        #pragma unroll
        for (int dt = 0; dt < 2; ++dt)
            #pragma unroll
            for (int r = 0; r < 4; ++r) {
                int row = q * 4 + r;
                float dn = __shfl(inv[g], row);    // lane 'row' holds denom for i-local=row
                float o = acc[g][dt][r] * dn;
                o = o > 0.f ? o : (__expf(o) - 1.f);
                size_t i = (size_t)(b * 512 + ibase + g * 16 + row);
                out[i * 256 + h * 32 + dt * 16 + ln] = o;
            }
}

// ---------------------------------------------------------------------------
extern "C" void kernel_launch(void* const* d_in, const int* in_sizes, int n_in,
                              void* d_out, int out_size, void* d_ws, size_t ws_size,
                              hipStream_t stream) {
    const float* x    = (const float*)d_in[0];   // (32,512,256)
    const float* W    = (const float*)d_in[1];   // (256,256)
    const float* attn = (const float*)d_in[2];   // (1,8,64)
    float* out = (float*)d_out;                  // (32,512,256)

    unsigned short* xf   = (unsigned short*)d_ws;             // f16 x, 8.39 MB
    unsigned short* wf   = xf + (size_t)32 * 512 * 256;       // f16 W, 131 KB
    unsigned short* wxtg = wf + 256 * 256;                    // f16 [bh][d][j], 8.39 MB

    cvt_f16<<<(XN_CHUNKS + WN_CHUNKS + 255) / 256, 256, 0, stream>>>(x, W, xf, wf);
    gemm_wxt<<<512, 256, 0, stream>>>(xf, wf, wxtg);
    gat_attn<<<512, 512, 0, stream>>>(wxtg, attn, out);
}